// Round 12
// baseline (342.236 us; speedup 1.0000x reference)
//
#include <hip/hip_runtime.h>
#include <hip/hip_bf16.h>

typedef __hip_bfloat16 bf16;
typedef __attribute__((ext_vector_type(8))) short short8;
typedef __attribute__((ext_vector_type(4))) float f32x4;

#define F_BIAS 1
#define F_RELU 2
#define F_RES  4

__device__ __forceinline__ void st_out(float* p, float v){ *p = v; }
__device__ __forceinline__ void st_out(bf16* p, float v){ *p = __float2bfloat16(v); }
__device__ __forceinline__ short f2bs(float f){
  bf16 h = __float2bfloat16(f);
  return *reinterpret_cast<short*>(&h);
}

// async global->LDS, 16 B per lane (flash/spatial staging only).
__device__ __forceinline__ void gl_lds16(const void* g, void* l){
  __builtin_amdgcn_global_load_lds(
      (const __attribute__((address_space(1))) void*)g,
      (__attribute__((address_space(3))) void*)l, 16, 0, 0);
}

// ---------------- prologue: weight prep + LN(x_T) + LN(x_S) ----------------
struct ProArgs {
  const float* wsrc[10];
  bf16* wdst[10];
  const float *xT, *xS, *tl1w, *tl1b, *sl1w, *sl1b;
  bf16 *hT, *hS;
};

__device__ void ln_body(bf16* __restrict__ dst, const float* __restrict__ src,
                        const float* __restrict__ w, const float* __restrict__ bvec,
                        int row, int rowLen){
  int tid = threadIdx.x;
  const float* s = src + (size_t)row*rowLen;
  float x0 = s[tid];
  float x1 = (rowLen > 256) ? s[tid+256] : 0.0f;
  float sum = x0 + x1, sq = x0*x0 + x1*x1;
  #pragma unroll
  for (int off=32; off; off>>=1){
    sum += __shfl_down(sum, off, 64);
    sq  += __shfl_down(sq , off, 64);
  }
  __shared__ float sbs[4], sbq[4];
  int wid = tid>>6, lane = tid&63;
  if (lane==0){ sbs[wid]=sum; sbq[wid]=sq; }
  __syncthreads();
  if (tid==0){
    float a=0, b2=0;
    for (int i=0;i<4;i++){ a+=sbs[i]; b2+=sbq[i]; }
    sbs[0]=a; sbq[0]=b2;
  }
  __syncthreads();
  float inv  = 1.0f/(float)rowLen;
  float mean = sbs[0]*inv;
  float var  = sbq[0]*inv - mean*mean;
  float rstd = rsqrtf(var + 1e-6f);
  bf16* d = dst + (size_t)row*rowLen;
  d[tid] = __float2bfloat16((x0-mean)*rstd*w[tid] + bvec[tid]);
  if (rowLen > 256)
    d[tid+256] = __float2bfloat16((x1-mean)*rstd*w[tid+256] + bvec[tid+256]);
}

__global__ __launch_bounds__(256) void prologue(ProArgs a){
  int blk = blockIdx.x;
  if (blk < 1792){
    int v = blk*256 + threadIdx.x;
    int e = v*4;
    int seg = (e>=65536)+(e>=131072)+(e>=196608)+(e>=262144)+(e>=524288)
            + (e>=786432)+(e>=1048576)+(e>=1310720)+(e>=1572864);
    const int starts[10] = {0,65536,131072,196608,262144,524288,786432,
                            1048576,1310720,1572864};
    int off = e - starts[seg];
    float4 f = *(const float4*)(a.wsrc[seg] + off);
    short4 o;
    o.x = f2bs(f.x); o.y = f2bs(f.y); o.z = f2bs(f.z); o.w = f2bs(f.w);
    *(short4*)((short*)a.wdst[seg] + off) = o;
  } else if (blk < 1792 + 8192){
    ln_body(a.hT, a.xT, a.tl1w, a.tl1b, blk-1792, 256);
  } else {
    ln_body(a.hS, a.xS, a.sl1w, a.sl1b, blk-9984, 512);
  }
}

// -------- MFMA bf16 GEMM, DIRECT from global/L2 (no LDS, no barriers) ------
// C[M,N] = A[M,K] @ B[N,K]^T. BN=128, 4 waves (2x2). Each wave loads its own
// fragments: one b128 load covers 16 rows x 64 B contiguous (quads 0..3).
// Wave-pairs re-read shared rows from L2 (~2x traffic) -- cheap vs barriers.
template<int BM>
__device__ __forceinline__ void gemm_body(
    const bf16* __restrict__ A, const bf16* __restrict__ B,
    float* __restrict__ outF, bf16* __restrict__ outB,
    const float* __restrict__ bias, const float* __restrict__ resid,
    int K, int lda, int ldb, int ldc, int flags, int m0, int n0){
  int tid = threadIdx.x;
  int w = tid>>6, lane = tid&63, quad = lane>>4, l16 = lane&15;
  constexpr int WM = BM/2;
  constexpr int MF = WM/16;
  int wm = (w>>1)*WM, wn = (w&1)*64;
  f32x4 acc[MF][4];
  #pragma unroll
  for (int r=0;r<MF;r++)
    #pragma unroll
    for (int j=0;j<4;j++)
      acc[r][j] = (f32x4){0.f,0.f,0.f,0.f};

  const bf16* Ab = A + (size_t)(m0+wm+l16)*lda + quad*8;
  const bf16* Bb = B + (size_t)(n0+wn+l16)*ldb + quad*8;
  #pragma unroll 2
  for (int k0 = 0; k0 < K; k0 += 32){
    short8 af[MF], bfr[4];
    #pragma unroll
    for (int r=0;r<MF;r++)
      af[r] = *(const short8*)(Ab + (size_t)r*16*lda + k0);
    #pragma unroll
    for (int j=0;j<4;j++)
      bfr[j] = *(const short8*)(Bb + (size_t)j*16*ldb + k0);
    #pragma unroll
    for (int r=0;r<MF;r++)
      #pragma unroll
      for (int j=0;j<4;j++)
        acc[r][j] = __builtin_amdgcn_mfma_f32_16x16x32_bf16(af[r], bfr[j], acc[r][j], 0,0,0);
  }
  #pragma unroll
  for (int r=0;r<MF;r++){
    int mb = m0 + wm + r*16 + quad*4;
    #pragma unroll
    for (int j=0;j<4;j++){
      int n = n0 + wn + j*16 + l16;
      float bv = (flags & F_BIAS) ? bias[n] : 0.0f;
      #pragma unroll
      for (int e=0;e<4;e++){
        float v = acc[r][j][e] + bv;
        if (flags & F_RELU) v = fmaxf(v, 0.0f);
        long long idx = (long long)(mb+e)*ldc + n;
        if (flags & F_RES) v += resid[idx];
        if (outF) outF[idx] = v;
        if (outB) st_out(outB + idx, v);
      }
    }
  }
}

template<int BM>
__global__ __launch_bounds__(256) void gemm_mfma(
    const bf16* __restrict__ A, const bf16* __restrict__ B,
    float* __restrict__ outF, bf16* __restrict__ outB,
    const float* __restrict__ bias, const float* __restrict__ resid,
    int K, int lda, int ldb, int ldc, int flags){
  gemm_body<BM>(A,B,outF,outB,bias,resid,K,lda,ldb,ldc,flags,
                blockIdx.x*BM, blockIdx.y*128);
}

// ---- dual GEMM: two independent <128> GEMMs in one launch (1-D grid) ------
struct GArgs {
  const bf16 *A, *B;
  float* outF; bf16* outB;
  const float *bias, *resid;
  int K, lda, ldb, ldc, flags, ty;
};
__global__ __launch_bounds__(256) void gemm_dual(GArgs g0, GArgs g1, int n0){
  int id = blockIdx.x;
  bool first = id < n0;
  const GArgs& g = first ? g0 : g1;
  int t = first ? id : id - n0;
  int bx = t / g.ty, by = t - bx*g.ty;
  gemm_body<128>(g.A, g.B, g.outF, g.outB, g.bias, g.resid,
                 g.K, g.lda, g.ldb, g.ldc, g.flags, bx*128, by*128);
}

// ------- direct MFMA GEMM + fused row-LN epilogue (BM=32, N=ldc=256) -------
__global__ __launch_bounds__(256) void gemm_ln(
    const bf16* __restrict__ A, const bf16* __restrict__ B,
    float* __restrict__ outF, bf16* __restrict__ outLN,
    const float* __restrict__ resid,
    const float* __restrict__ lnw, const float* __restrict__ lnb,
    int K, int lda, int ldb, int flags,
    long long sA, long long sB, long long sO, long long sR){
  int bz = blockIdx.z;
  A += (size_t)bz*sA;
  B += (size_t)bz*sB;
  long long obase = (long long)bz*sO;
  __shared__ float redS[2][32], redQ[2][32];
  int tid = threadIdx.x;
  int m0 = blockIdx.x*32;
  int w = tid>>6, lane = tid&63, quad = lane>>4, l16 = lane&15;
  int wm = (w>>1)*16, wn = (w&1)*128;
  f32x4 acc[8];
  #pragma unroll
  for (int j=0;j<8;j++) acc[j] = (f32x4){0.f,0.f,0.f,0.f};

  const bf16* Ab = A + (size_t)(m0+wm+l16)*lda + quad*8;
  const bf16* Bb = B + (size_t)(wn+l16)*ldb + quad*8;
  #pragma unroll 2
  for (int k0 = 0; k0 < K; k0 += 32){
    short8 af = *(const short8*)(Ab + k0);
    short8 bfr[8];
    #pragma unroll
    for (int j=0;j<8;j++)
      bfr[j] = *(const short8*)(Bb + (size_t)j*16*ldb + k0);
    #pragma unroll
    for (int j=0;j<8;j++)
      acc[j] = __builtin_amdgcn_mfma_f32_16x16x32_bf16(af, bfr[j], acc[j], 0,0,0);
  }
  #pragma unroll
  for (int e=0;e<4;e++){
    int row = wm + quad*4 + e;
    float s = 0.f, q2 = 0.f;
    #pragma unroll
    for (int j=0;j<8;j++){
      float v = acc[j][e];
      if (flags & F_RES)
        v += resid[(long long)bz*sR + (long long)(m0+row)*256 + wn + j*16 + l16];
      acc[j][e] = v;
      s += v; q2 += v*v;
    }
    #pragma unroll
    for (int off=1; off<16; off<<=1){
      s  += __shfl_xor(s , off, 16);
      q2 += __shfl_xor(q2, off, 16);
    }
    if (l16==0){ redS[w&1][row] = s; redQ[w&1][row] = q2; }
  }
  __syncthreads();
  #pragma unroll
  for (int e=0;e<4;e++){
    int row = wm + quad*4 + e;
    float tot = redS[0][row] + redS[1][row];
    float tq  = redQ[0][row] + redQ[1][row];
    float mean = tot * (1.0f/256.0f);
    float var  = tq * (1.0f/256.0f) - mean*mean;
    float rstd = rsqrtf(var + 1e-6f);
    #pragma unroll
    for (int j=0;j<8;j++){
      int col = wn + j*16 + l16;
      float v = acc[j][e];
      long long idx = obase + (long long)(m0+row)*256 + col;
      if (outF) outF[idx] = v;
      outLN[idx] = __float2bfloat16((v-mean)*rstd*lnw[col] + lnb[col]);
    }
  }
}

// ---------------- MFMA flash temporal causal attention (proven) ------------
__device__ __forceinline__ int fsw(int row){ return (row>>1)&3; }
__global__ __launch_bounds__(256) void flash_mfma(
    const bf16* __restrict__ qkv, bf16* __restrict__ o){
  int qt = (int)gridDim.x - 1 - (int)blockIdx.x;
  int h = blockIdx.y, b = blockIdx.z;
  int tid = threadIdx.x;
  int w = tid>>6, lane = tid&63, quad = lane>>4, l16 = lane&15;
  __shared__ bf16 Qs[64*32];
  __shared__ bf16 Ks[64*32];
  __shared__ bf16 Vt[32*72];
  __shared__ bf16 Ps[64*72];
  const bf16* base = qkv + (size_t)b*512*768;
  int t0 = qt*64;
  int srow = tid>>2, spos = tid&3;
  gl_lds16(base + (size_t)(t0+srow)*768 + h*32 + ((spos ^ fsw(srow))*8),
           &Qs[srow*32 + spos*8]);
  f32x4 accO[2];
  accO[0] = (f32x4){0.f,0.f,0.f,0.f};
  accO[1] = (f32x4){0.f,0.f,0.f,0.f};
  float m_i[4], l_i[4];
  #pragma unroll
  for (int e=0;e<4;e++){ m_i[e] = -3.0e38f; l_i[e] = 0.0f; }
  const float scale = 0.17677669529663687f;

  for (int kt = 0; kt <= qt; ++kt){
    int s0 = kt*64;
    __syncthreads();
    {
      const bf16* rp = base + (size_t)(s0+srow)*768 + h*32;
      gl_lds16(rp + 256 + ((spos ^ fsw(srow))*8), &Ks[srow*32 + spos*8]);
      short8 v = *(const short8*)(rp + 512 + spos*8);
      #pragma unroll
      for (int q=0;q<8;q++){
        short tmp = v[q];
        Vt[(spos*8+q)*72 + srow] = *(bf16*)&tmp;
      }
    }
    __syncthreads();
    int rq = w*16 + l16;
    short8 aq = *(short8*)&Qs[rq*32 + ((quad ^ fsw(rq))*8)];
    f32x4 S[4];
    #pragma unroll
    for (int j2=0;j2<4;j2++){
      int rk = j2*16 + l16;
      short8 bk = *(short8*)&Ks[rk*32 + ((quad ^ fsw(rk))*8)];
      S[j2] = __builtin_amdgcn_mfma_f32_16x16x32_bf16(aq, bk,
                (f32x4){0.f,0.f,0.f,0.f}, 0,0,0);
    }
    bool diag = (kt == qt);
    int qrow_base = t0 + w*16 + quad*4;
    #pragma unroll
    for (int e=0;e<4;e++){
      float sv[4];
      #pragma unroll
      for (int j2=0;j2<4;j2++){
        float x = S[j2][e]*scale;
        if (diag && (s0 + j2*16 + l16 > qrow_base + e)) x = -3.0e38f;
        sv[j2] = x;
      }
      float mx = fmaxf(fmaxf(sv[0],sv[1]), fmaxf(sv[2],sv[3]));
      #pragma unroll
      for (int off=1; off<16; off<<=1) mx = fmaxf(mx, __shfl_xor(mx, off, 64));
      float m_new = fmaxf(m_i[e], mx);
      float alpha = __expf(m_i[e]-m_new);
      float rs = 0.0f;
      #pragma unroll
      for (int j2=0;j2<4;j2++){
        float p = __expf(sv[j2]-m_new);
        rs += p;
        Ps[(w*16+quad*4+e)*72 + j2*16 + l16] = __float2bfloat16(p);
      }
      #pragma unroll
      for (int off=1; off<16; off<<=1) rs += __shfl_xor(rs, off, 64);
      l_i[e] = l_i[e]*alpha + rs;
      m_i[e] = m_new;
      accO[0][e] *= alpha;
      accO[1][e] *= alpha;
    }
    __syncthreads();
    #pragma unroll
    for (int sh=0; sh<2; ++sh){
      short8 ap = *(short8*)&Ps[(w*16+l16)*72 + sh*32 + quad*8];
      #pragma unroll
      for (int dh=0; dh<2; ++dh){
        short8 bv = *(short8*)&Vt[(dh*16+l16)*72 + sh*32 + quad*8];
        accO[dh] = __builtin_amdgcn_mfma_f32_16x16x32_bf16(ap, bv, accO[dh], 0,0,0);
      }
    }
  }
  #pragma unroll
  for (int e=0;e<4;e++){
    float inv = 1.0f/l_i[e];
    int t = t0 + w*16 + quad*4 + e;
    bf16* op = o + ((size_t)(b*512+t))*256 + h*32 + l16;
    op[0]  = __float2bfloat16(accO[0][e]*inv);
    op[16] = __float2bfloat16(accO[1][e]*inv);
  }
}

// ------- fused spatial attention body (scores + softmax + head-mean) -------
__device__ void spatial_body(const bf16* __restrict__ qk,
                             float* __restrict__ out1, bf16* __restrict__ swB,
                             int ct, int b){
  int tid = threadIdx.x;
  int w = tid>>6, lane = tid&63, quad = lane>>4, l16 = lane&15;
  __shared__ bf16 Qall[16*512];
  __shared__ bf16 Ks[256*64];
  __shared__ float redM[4][16], redS2[4][16];
  const bf16* qbase = qk + ((size_t)(b*256 + ct*16))*1024;
  #pragma unroll
  for (int c=0;c<4;c++){
    int ch = tid + c*256;
    int row = ch>>6, p = ch&63;
    gl_lds16(qbase + (size_t)row*1024 + ((p ^ (row&7))*8), &Qall[row*512 + p*8]);
  }
  float fRes[4][4];
  #pragma unroll
  for (int j=0;j<4;j++)
    #pragma unroll
    for (int e=0;e<4;e++) fRes[j][e] = 0.0f;

  for (int h=0; h<8; ++h){
    __syncthreads();
    #pragma unroll
    for (int c=0;c<8;c++){
      int ch = tid + c*256;
      int e = ch>>3, p = ch&7;
      gl_lds16(qk + ((size_t)(b*256 + e))*1024 + 512 + h*64 + ((p ^ (e&7))*8),
               &Ks[e*64 + p*8]);
    }
    __syncthreads();
    f32x4 acc[4];
    #pragma unroll
    for (int j=0;j<4;j++) acc[j] = (f32x4){0.f,0.f,0.f,0.f};
    #pragma unroll
    for (int ks=0; ks<2; ++ks){
      int g = h*8 + ks*4 + quad;
      short8 aq = *(short8*)&Qall[l16*512 + ((g ^ (l16&7))*8)];
      #pragma unroll
      for (int j=0;j<4;j++){
        int e = w*64 + j*16 + l16;
        short8 bk = *(short8*)&Ks[e*64 + (((ks*4+quad) ^ (e&7))*8)];
        acc[j] = __builtin_amdgcn_mfma_f32_16x16x32_bf16(aq, bk, acc[j], 0,0,0);
      }
    }
    #pragma unroll
    for (int e=0;e<4;e++){
      float m = -3.0e38f;
      #pragma unroll
      for (int j=0;j<4;j++){
        float s = acc[j][e]*0.125f;
        acc[j][e] = s;
        m = fmaxf(m, s);
      }
      #pragma unroll
      for (int off=1; off<16; off<<=1) m = fmaxf(m, __shfl_xor(m, off, 16));
      if (l16==0) redM[w][quad*4+e] = m;
    }
    __syncthreads();
    #pragma unroll
    for (int e=0;e<4;e++){
      int r = quad*4+e;
      float m = fmaxf(fmaxf(redM[0][r],redM[1][r]), fmaxf(redM[2][r],redM[3][r]));
      float s = 0.0f;
      #pragma unroll
      for (int j=0;j<4;j++){
        float p = __expf(acc[j][e]-m);
        acc[j][e] = p; s += p;
      }
      #pragma unroll
      for (int off=1; off<16; off<<=1) s += __shfl_xor(s, off, 16);
      if (l16==0) redS2[w][r] = s;
    }
    __syncthreads();
    #pragma unroll
    for (int e=0;e<4;e++){
      int r = quad*4+e;
      float tot = redS2[0][r]+redS2[1][r]+redS2[2][r]+redS2[3][r];
      float inv = 0.125f/tot;
      #pragma unroll
      for (int j=0;j<4;j++) fRes[j][e] += acc[j][e]*inv;
    }
  }
  #pragma unroll
  for (int e=0;e<4;e++){
    int c = ct*16 + quad*4 + e;
    size_t rb = ((size_t)b*256 + c)*256;
    #pragma unroll
    for (int j=0;j<4;j++){
      int col = w*64 + j*16 + l16;
      out1[rb+col] = fRes[j][e];
      swB[rb+col]  = __float2bfloat16(fRes[j][e]);
    }
  }
}

// ---- mixed launch: f1b GEMM (256 tiles) + spatial_fused (256 blocks) ------
__global__ __launch_bounds__(256) void mixed_l2(
    const bf16* __restrict__ gA, const bf16* __restrict__ gB,
    float* __restrict__ gOutF, bf16* __restrict__ gOutB,
    const float* __restrict__ gBias, const float* __restrict__ gResid,
    const bf16* __restrict__ qk, float* __restrict__ out1,
    bf16* __restrict__ swB){
  int id = blockIdx.x;
  if (id < 256){
    int bx = id >> 1, by = id & 1;
    gemm_body<64>(gA, gB, gOutF, gOutB, gBias, gResid,
                  1024, 1024, 1024, 256, F_BIAS|F_RES, bx*64, by*128);
  } else {
    int t = id - 256;
    spatial_body(qk, out1, swB, t & 15, t >> 4);
  }
}

extern "C" void kernel_launch(void* const* d_in, const int* in_sizes, int n_in,
                              void* d_out, int out_size, void* d_ws, size_t ws_size,
                              hipStream_t stream){
  (void)in_sizes; (void)n_in; (void)out_size; (void)ws_size;
  const float* x_T  = (const float*)d_in[0];
  const float* x_S  = (const float*)d_in[1];
  const float* Wq_t = (const float*)d_in[2];
  const float* Wk_t = (const float*)d_in[3];
  const float* Wv_t = (const float*)d_in[4];
  const float* Wo   = (const float*)d_in[5];
  const float* Wq_s = (const float*)d_in[6];
  const float* Wk_s = (const float*)d_in[7];
  const float* f1w1 = (const float*)d_in[8];
  const float* f1b1 = (const float*)d_in[9];
  const float* f1w2 = (const float*)d_in[10];
  const float* f1b2 = (const float*)d_in[11];
  const float* f2w1 = (const float*)d_in[12];
  const float* f2b1 = (const float*)d_in[13];
  const float* f2w2 = (const float*)d_in[14];
  const float* f2b2 = (const float*)d_in[15];
  const float* tl1w = (const float*)d_in[16];
  const float* tl1b = (const float*)d_in[17];
  const float* tl2w = (const float*)d_in[18];
  const float* tl2b = (const float*)d_in[19];
  const float* sl1w = (const float*)d_in[20];
  const float* sl1b = (const float*)d_in[21];
  const float* flw  = (const float*)d_in[22];
  const float* flb  = (const float*)d_in[23];

  float* ws = (float*)d_ws;
  size_t off = 0;
  bf16*  Wqkvb  = (bf16*)(ws + off); off += 768*256/2;
  bf16*  Wob    = (bf16*)(ws + off); off += 256*256/2;
  bf16*  f1w1b  = (bf16*)(ws + off); off += 1024*256/2;
  bf16*  f1w2b  = (bf16*)(ws + off); off += 256*1024/2;
  bf16*  f2w1b  = (bf16*)(ws + off); off += 1024*256/2;
  bf16*  f2w2b  = (bf16*)(ws + off); off += 256*1024/2;
  bf16*  WSb    = (bf16*)(ws + off); off += 1024*512/2;
  bf16*  bufHb  = (bf16*)(ws + off); off += (size_t)8192*256/2;
  bf16*  bufHSb = (bf16*)(ws + off); off += (size_t)4096*512/2;
  bf16*  bufQKVb= (bf16*)(ws + off); off += (size_t)8192*768/2;
  bf16*  bufBigB= (bf16*)(ws + off); off += (size_t)8192*1024/2;
  bf16*  bufOb  = (bf16*)(ws + off); off += (size_t)8192*256/2;
  bf16*  bufTOb = (bf16*)(ws + off); off += (size_t)8192*256/2;
  bf16*  swB    = (bf16*)(ws + off); off += (size_t)16*256*256/2;
  bf16*  qkB    = (bf16*)(ws + off); off += (size_t)4096*1024/2;
  float* bufX   = ws + off; off += (size_t)8192*256;
  float* bufTO  = ws + off; off += (size_t)8192*256;
  float* bufX2  = ws + off; off += (size_t)8192*256;

  float* out0 = (float*)d_out;                      // [B,T,C]
  float* out1 = out0 + (size_t)16*512*256;          // spatial_weights [B,C,C]

  // 1. prologue: weight prep + LN(x_T) + LN(x_S)
  ProArgs pa;
  pa.wsrc[0]=Wq_t;  pa.wdst[0]=Wqkvb;
  pa.wsrc[1]=Wk_t;  pa.wdst[1]=Wqkvb+65536;
  pa.wsrc[2]=Wv_t;  pa.wdst[2]=Wqkvb+131072;
  pa.wsrc[3]=Wo;    pa.wdst[3]=Wob;
  pa.wsrc[4]=f1w1;  pa.wdst[4]=f1w1b;
  pa.wsrc[5]=f1w2;  pa.wdst[5]=f1w2b;
  pa.wsrc[6]=f2w1;  pa.wdst[6]=f2w1b;
  pa.wsrc[7]=f2w2;  pa.wdst[7]=f2w2b;
  pa.wsrc[8]=Wq_s;  pa.wdst[8]=WSb;
  pa.wsrc[9]=Wk_s;  pa.wdst[9]=WSb+262144;
  pa.xT=x_T; pa.xS=x_S; pa.tl1w=tl1w; pa.tl1b=tl1b;
  pa.sl1w=sl1w; pa.sl1b=sl1b; pa.hT=bufHb; pa.hS=bufHSb;
  prologue<<<14080,256,0,stream>>>(pa);

  // 2. dual: qkv (384 tiles) + spatial projection (256 tiles)
  GArgs gq, gs;
  gq.A=bufHb;  gq.B=Wqkvb; gq.outF=nullptr; gq.outB=bufQKVb;
  gq.bias=nullptr; gq.resid=nullptr;
  gq.K=256; gq.lda=256; gq.ldb=256; gq.ldc=768; gq.flags=0; gq.ty=6;
  gs.A=bufHSb; gs.B=WSb;   gs.outF=nullptr; gs.outB=qkB;
  gs.bias=nullptr; gs.resid=nullptr;
  gs.K=512; gs.lda=512; gs.ldb=512; gs.ldc=1024; gs.flags=0; gs.ty=8;
  gemm_dual<<<640,256,0,stream>>>(gq, gs, 384);

  // 3. temporal causal flash attention -> bf16 o
  flash_mfma<<<dim3(8,8,16),256,0,stream>>>(bufQKVb, bufOb);
  // 4. x = o @ Wo^T + x_T ; h2 = LN(x)  (fused, BM=32, 256 blocks)
  gemm_ln<<<dim3(256,1,1),256,0,stream>>>(bufOb, Wob, bufX, bufHb,
        x_T, tl2w, tl2b, 256, 256,256, F_RES, 0,0,0,0);
  // 5. f1 = relu(h2 @ w1^T + b1) -> bf16
  gemm_mfma<128><<<dim3(64,8),256,0,stream>>>(bufHb, f1w1b, nullptr, bufBigB,
        f1b1, nullptr, 256, 256,256,1024, F_BIAS|F_RELU);
  // 6. mixed: temporal_out GEMM (f1b) + fused spatial attention
  mixed_l2<<<512,256,0,stream>>>(bufBigB, f1w2b, bufTO, bufTOb, f1b2, bufX,
        qkB, out1, swB);
  // 7. x2 = TO @ sw[b]^T + TO ; h3 = LN(x2)  (fused, batched, 256 blocks)
  gemm_ln<<<dim3(16,1,16),256,0,stream>>>(bufTOb, swB, bufX2, bufHb,
        bufTO, flw, flb, 256, 256,256, F_RES,
        131072, 65536, 131072, 131072);
  // 8. f2 hidden -> bf16
  gemm_mfma<128><<<dim3(64,8),256,0,stream>>>(bufHb, f2w1b, nullptr, bufBigB,
        f2b1, nullptr, 256, 256,256,1024, F_BIAS|F_RELU);
  // 9. out = f2 @ w2^T + b2 + x2 -> fp32 d_out
  gemm_mfma<64><<<dim3(128,2),256,0,stream>>>(bufBigB, f2w2b, out0, nullptr,
        f2b2, bufX2, 1024, 1024,1024,256, F_BIAS|F_RES);
}

// Round 13
// 300.192 us; speedup vs baseline: 1.1401x; 1.1401x over previous
//
#include <hip/hip_runtime.h>
#include <hip/hip_bf16.h>

typedef __hip_bfloat16 bf16;
typedef __attribute__((ext_vector_type(8))) short short8;
typedef __attribute__((ext_vector_type(4))) float f32x4;

#define F_BIAS 1
#define F_RELU 2
#define F_RES  4

__device__ __forceinline__ void st_out(float* p, float v){ *p = v; }
__device__ __forceinline__ void st_out(bf16* p, float v){ *p = __float2bfloat16(v); }
__device__ __forceinline__ short f2bs(float f){
  bf16 h = __float2bfloat16(f);
  return *reinterpret_cast<short*>(&h);
}

// async global->LDS, 16 B per lane.
__device__ __forceinline__ void gl_lds16(const void* g, void* l){
  __builtin_amdgcn_global_load_lds(
      (const __attribute__((address_space(1))) void*)g,
      (__attribute__((address_space(3))) void*)l, 16, 0, 0);
}

// ---------------- prologue: weight prep + LN(x_T) + LN(x_S) ----------------
struct ProArgs {
  const float* wsrc[10];
  bf16* wdst[10];
  const float *xT, *xS, *tl1w, *tl1b, *sl1w, *sl1b;
  bf16 *hT, *hS;
};

__device__ void ln_body(bf16* __restrict__ dst, const float* __restrict__ src,
                        const float* __restrict__ w, const float* __restrict__ bvec,
                        int row, int rowLen){
  int tid = threadIdx.x;
  const float* s = src + (size_t)row*rowLen;
  float x0 = s[tid];
  float x1 = (rowLen > 256) ? s[tid+256] : 0.0f;
  float sum = x0 + x1, sq = x0*x0 + x1*x1;
  #pragma unroll
  for (int off=32; off; off>>=1){
    sum += __shfl_down(sum, off, 64);
    sq  += __shfl_down(sq , off, 64);
  }
  __shared__ float sbs[4], sbq[4];
  int wid = tid>>6, lane = tid&63;
  if (lane==0){ sbs[wid]=sum; sbq[wid]=sq; }
  __syncthreads();
  if (tid==0){
    float a=0, b2=0;
    for (int i=0;i<4;i++){ a+=sbs[i]; b2+=sbq[i]; }
    sbs[0]=a; sbq[0]=b2;
  }
  __syncthreads();
  float inv  = 1.0f/(float)rowLen;
  float mean = sbs[0]*inv;
  float var  = sbq[0]*inv - mean*mean;
  float rstd = rsqrtf(var + 1e-6f);
  bf16* d = dst + (size_t)row*rowLen;
  d[tid] = __float2bfloat16((x0-mean)*rstd*w[tid] + bvec[tid]);
  if (rowLen > 256)
    d[tid+256] = __float2bfloat16((x1-mean)*rstd*w[tid+256] + bvec[tid+256]);
}

__global__ __launch_bounds__(256) void prologue(ProArgs a){
  int blk = blockIdx.x;
  if (blk < 1792){
    int v = blk*256 + threadIdx.x;
    int e = v*4;
    int seg = (e>=65536)+(e>=131072)+(e>=196608)+(e>=262144)+(e>=524288)
            + (e>=786432)+(e>=1048576)+(e>=1310720)+(e>=1572864);
    const int starts[10] = {0,65536,131072,196608,262144,524288,786432,
                            1048576,1310720,1572864};
    int off = e - starts[seg];
    float4 f = *(const float4*)(a.wsrc[seg] + off);
    short4 o;
    o.x = f2bs(f.x); o.y = f2bs(f.y); o.z = f2bs(f.z); o.w = f2bs(f.w);
    *(short4*)((short*)a.wdst[seg] + off) = o;
  } else if (blk < 1792 + 8192){
    ln_body(a.hT, a.xT, a.tl1w, a.tl1b, blk-1792, 256);
  } else {
    ln_body(a.hS, a.xS, a.sl1w, a.sl1b, blk-9984, 512);
  }
}

// ---------------- MFMA bf16 GEMM body (swizzled gl_lds16, BN=128) ----------
// R11-proven LDS structure. 256 threads = 4 waves (2x2).
template<int BM, int BK>
__device__ __forceinline__ void gemm_body(
    const bf16* __restrict__ A, const bf16* __restrict__ B,
    float* __restrict__ outF, bf16* __restrict__ outB,
    const float* __restrict__ bias, const float* __restrict__ resid,
    int K, int lda, int ldb, int ldc, int flags, int m0, int n0){
  __shared__ short As[BM*BK];
  __shared__ short Bs[128*BK];
  int tid = threadIdx.x;
  int w = tid>>6, lane = tid&63, quad = lane>>4, l16 = lane&15;
  constexpr int WM = BM/2;
  constexpr int MF = WM/16;
  constexpr int CPR = BK/8;
  constexpr int CA = BM*CPR/256;
  constexpr int CB = 128*CPR/256;
  int wm = (w>>1)*WM, wn = (w&1)*64;
  f32x4 acc[MF][4];
  #pragma unroll
  for (int r=0;r<MF;r++)
    #pragma unroll
    for (int j=0;j<4;j++)
      acc[r][j] = (f32x4){0.f,0.f,0.f,0.f};

  for (int k0 = 0; k0 < K; k0 += BK){
    #pragma unroll
    for (int c=0;c<CA;c++){
      int ch = tid + c*256;
      int row = ch / CPR, p = ch % CPR;
      gl_lds16(A + (size_t)(m0+row)*lda + k0 + ((p ^ (row&(CPR-1)))*8),
               &As[row*BK + p*8]);
    }
    #pragma unroll
    for (int c=0;c<CB;c++){
      int ch = tid + c*256;
      int row = ch / CPR, p = ch % CPR;
      gl_lds16(B + (size_t)(n0+row)*ldb + k0 + ((p ^ (row&(CPR-1)))*8),
               &Bs[row*BK + p*8]);
    }
    __syncthreads();
    #pragma unroll
    for (int ks=0; ks<BK/32; ++ks){
      short8 af[MF], bfr[4];
      #pragma unroll
      for (int r=0;r<MF;r++){
        int rr = wm + r*16 + l16;
        af[r] = *(short8*)&As[rr*BK + (((ks*4+quad) ^ (rr&(CPR-1)))*8)];
      }
      #pragma unroll
      for (int j=0;j<4;j++){
        int rr = wn + j*16 + l16;
        bfr[j] = *(short8*)&Bs[rr*BK + (((ks*4+quad) ^ (rr&(CPR-1)))*8)];
      }
      #pragma unroll
      for (int r=0;r<MF;r++)
        #pragma unroll
        for (int j=0;j<4;j++)
          acc[r][j] = __builtin_amdgcn_mfma_f32_16x16x32_bf16(af[r], bfr[j], acc[r][j], 0,0,0);
    }
    __syncthreads();
  }
  #pragma unroll
  for (int r=0;r<MF;r++){
    int mb = m0 + wm + r*16 + quad*4;
    #pragma unroll
    for (int j=0;j<4;j++){
      int n = n0 + wn + j*16 + l16;
      float bv = (flags & F_BIAS) ? bias[n] : 0.0f;
      #pragma unroll
      for (int e=0;e<4;e++){
        float v = acc[r][j][e] + bv;
        if (flags & F_RELU) v = fmaxf(v, 0.0f);
        long long idx = (long long)(mb+e)*ldc + n;
        if (flags & F_RES) v += resid[idx];
        if (outF) outF[idx] = v;
        if (outB) st_out(outB + idx, v);
      }
    }
  }
}

template<int BM, int BK>
__global__ __launch_bounds__(256) void gemm_mfma(
    const bf16* __restrict__ A, const bf16* __restrict__ B,
    float* __restrict__ outF, bf16* __restrict__ outB,
    const float* __restrict__ bias, const float* __restrict__ resid,
    int K, int lda, int ldb, int ldc, int flags){
  gemm_body<BM,BK>(A,B,outF,outB,bias,resid,K,lda,ldb,ldc,flags,
                   blockIdx.x*BM, blockIdx.y*128);
}

// ---- dual GEMM: two independent <128,64> GEMMs in one launch (1-D grid) ----
struct GArgs {
  const bf16 *A, *B;
  float* outF; bf16* outB;
  const float *bias, *resid;
  int K, lda, ldb, ldc, flags, ty;
};
__global__ __launch_bounds__(256) void gemm_dual(GArgs g0, GArgs g1, int n0){
  int id = blockIdx.x;
  bool first = id < n0;
  const GArgs& g = first ? g0 : g1;
  int t = first ? id : id - n0;
  int bx = t / g.ty, by = t - bx*g.ty;
  gemm_body<128,64>(g.A, g.B, g.outF, g.outB, g.bias, g.resid,
                    g.K, g.lda, g.ldb, g.ldc, g.flags, bx*128, by*128);
}

// ------- MFMA GEMM + fused row-LN epilogue (BM=32, N=ldc=256, BK=64) -------
__global__ __launch_bounds__(256) void gemm_ln(
    const bf16* __restrict__ A, const bf16* __restrict__ B,
    float* __restrict__ outF, bf16* __restrict__ outLN,
    const float* __restrict__ resid,
    const float* __restrict__ lnw, const float* __restrict__ lnb,
    int K, int lda, int ldb, int flags,
    long long sA, long long sB, long long sO, long long sR){
  int bz = blockIdx.z;
  A += (size_t)bz*sA;
  B += (size_t)bz*sB;
  long long obase = (long long)bz*sO;
  __shared__ short As[32*64];
  __shared__ short Bs[256*64];
  __shared__ float redS[2][32], redQ[2][32];
  int tid = threadIdx.x;
  int m0 = blockIdx.x*32;
  int w = tid>>6, lane = tid&63, quad = lane>>4, l16 = lane&15;
  int wm = (w>>1)*16, wn = (w&1)*128;
  f32x4 acc[8];
  #pragma unroll
  for (int j=0;j<8;j++) acc[j] = (f32x4){0.f,0.f,0.f,0.f};

  for (int k0 = 0; k0 < K; k0 += 64){
    {
      int row = tid >> 3, p = tid & 7;
      gl_lds16(A + (size_t)(m0+row)*lda + k0 + ((p ^ (row&7))*8),
               &As[row*64 + p*8]);
    }
    #pragma unroll
    for (int c=0;c<8;c++){
      int ch = tid + c*256;
      int row = ch >> 3, p = ch & 7;
      gl_lds16(B + (size_t)row*ldb + k0 + ((p ^ (row&7))*8),
               &Bs[row*64 + p*8]);
    }
    __syncthreads();
    #pragma unroll
    for (int ks=0; ks<2; ++ks){
      int rr = wm + l16;
      short8 af = *(short8*)&As[rr*64 + (((ks*4+quad) ^ (rr&7))*8)];
      #pragma unroll
      for (int j=0;j<8;j++){
        int rb = wn + j*16 + l16;
        short8 bfr = *(short8*)&Bs[rb*64 + (((ks*4+quad) ^ (rb&7))*8)];
        acc[j] = __builtin_amdgcn_mfma_f32_16x16x32_bf16(af, bfr, acc[j], 0,0,0);
      }
    }
    __syncthreads();
  }
  #pragma unroll
  for (int e=0;e<4;e++){
    int row = wm + quad*4 + e;
    float s = 0.f, q2 = 0.f;
    #pragma unroll
    for (int j=0;j<8;j++){
      float v = acc[j][e];
      if (flags & F_RES)
        v += resid[(long long)bz*sR + (long long)(m0+row)*256 + wn + j*16 + l16];
      acc[j][e] = v;
      s += v; q2 += v*v;
    }
    #pragma unroll
    for (int off=1; off<16; off<<=1){
      s  += __shfl_xor(s , off, 16);
      q2 += __shfl_xor(q2, off, 16);
    }
    if (l16==0){ redS[w&1][row] = s; redQ[w&1][row] = q2; }
  }
  __syncthreads();
  #pragma unroll
  for (int e=0;e<4;e++){
    int row = wm + quad*4 + e;
    float tot = redS[0][row] + redS[1][row];
    float tq  = redQ[0][row] + redQ[1][row];
    float mean = tot * (1.0f/256.0f);
    float var  = tq * (1.0f/256.0f) - mean*mean;
    float rstd = rsqrtf(var + 1e-6f);
    #pragma unroll
    for (int j=0;j<8;j++){
      int col = wn + j*16 + l16;
      float v = acc[j][e];
      long long idx = obase + (long long)(m0+row)*256 + col;
      if (outF) outF[idx] = v;
      outLN[idx] = __float2bfloat16((v-mean)*rstd*lnw[col] + lnb[col]);
    }
  }
}

// ---------------- flash body (R11-proven), smem passed in ------------------
__device__ __forceinline__ int fsw(int row){ return (row>>1)&3; }
__device__ void flash_body(const bf16* __restrict__ qkv, bf16* __restrict__ o,
                           int qt, int h, int b, char* smem){
  bf16* Qs = (bf16*)smem;            // 64*32  (4096 B)
  bf16* Ks = (bf16*)(smem + 4096);   // 64*32  (4096 B)
  bf16* Vt = (bf16*)(smem + 8192);   // 32*72  (4608 B)
  bf16* Ps = (bf16*)(smem + 12800);  // 64*72  (9216 B)
  int tid = threadIdx.x;
  int w = tid>>6, lane = tid&63, quad = lane>>4, l16 = lane&15;
  const bf16* base = qkv + (size_t)b*512*768;
  int t0 = qt*64;
  int srow = tid>>2, spos = tid&3;
  gl_lds16(base + (size_t)(t0+srow)*768 + h*32 + ((spos ^ fsw(srow))*8),
           &Qs[srow*32 + spos*8]);
  f32x4 accO[2];
  accO[0] = (f32x4){0.f,0.f,0.f,0.f};
  accO[1] = (f32x4){0.f,0.f,0.f,0.f};
  float m_i[4], l_i[4];
  #pragma unroll
  for (int e=0;e<4;e++){ m_i[e] = -3.0e38f; l_i[e] = 0.0f; }
  const float scale = 0.17677669529663687f;

  for (int kt = 0; kt <= qt; ++kt){
    int s0 = kt*64;
    __syncthreads();
    {
      const bf16* rp = base + (size_t)(s0+srow)*768 + h*32;
      gl_lds16(rp + 256 + ((spos ^ fsw(srow))*8), &Ks[srow*32 + spos*8]);
      short8 v = *(const short8*)(rp + 512 + spos*8);
      #pragma unroll
      for (int q=0;q<8;q++){
        short tmp = v[q];
        Vt[(spos*8+q)*72 + srow] = *(bf16*)&tmp;
      }
    }
    __syncthreads();
    int rq = w*16 + l16;
    short8 aq = *(short8*)&Qs[rq*32 + ((quad ^ fsw(rq))*8)];
    f32x4 S[4];
    #pragma unroll
    for (int j2=0;j2<4;j2++){
      int rk = j2*16 + l16;
      short8 bk = *(short8*)&Ks[rk*32 + ((quad ^ fsw(rk))*8)];
      S[j2] = __builtin_amdgcn_mfma_f32_16x16x32_bf16(aq, bk,
                (f32x4){0.f,0.f,0.f,0.f}, 0,0,0);
    }
    bool diag = (kt == qt);
    int qrow_base = t0 + w*16 + quad*4;
    #pragma unroll
    for (int e=0;e<4;e++){
      float sv[4];
      #pragma unroll
      for (int j2=0;j2<4;j2++){
        float x = S[j2][e]*scale;
        if (diag && (s0 + j2*16 + l16 > qrow_base + e)) x = -3.0e38f;
        sv[j2] = x;
      }
      float mx = fmaxf(fmaxf(sv[0],sv[1]), fmaxf(sv[2],sv[3]));
      #pragma unroll
      for (int off=1; off<16; off<<=1) mx = fmaxf(mx, __shfl_xor(mx, off, 64));
      float m_new = fmaxf(m_i[e], mx);
      float alpha = __expf(m_i[e]-m_new);
      float rs = 0.0f;
      #pragma unroll
      for (int j2=0;j2<4;j2++){
        float p = __expf(sv[j2]-m_new);
        rs += p;
        Ps[(w*16+quad*4+e)*72 + j2*16 + l16] = __float2bfloat16(p);
      }
      #pragma unroll
      for (int off=1; off<16; off<<=1) rs += __shfl_xor(rs, off, 64);
      l_i[e] = l_i[e]*alpha + rs;
      m_i[e] = m_new;
      accO[0][e] *= alpha;
      accO[1][e] *= alpha;
    }
    __syncthreads();
    #pragma unroll
    for (int sh=0; sh<2; ++sh){
      short8 ap = *(short8*)&Ps[(w*16+l16)*72 + sh*32 + quad*8];
      #pragma unroll
      for (int dh=0; dh<2; ++dh){
        short8 bv = *(short8*)&Vt[(dh*16+l16)*72 + sh*32 + quad*8];
        accO[dh] = __builtin_amdgcn_mfma_f32_16x16x32_bf16(ap, bv, accO[dh], 0,0,0);
      }
    }
  }
  #pragma unroll
  for (int e=0;e<4;e++){
    float inv = 1.0f/l_i[e];
    int t = t0 + w*16 + quad*4 + e;
    bf16* op = o + ((size_t)(b*512+t))*256 + h*32 + l16;
    op[0]  = __float2bfloat16(accO[0][e]*inv);
    op[16] = __float2bfloat16(accO[1][e]*inv);
  }
}

// ------- spatial body (R11-proven), smem passed in -------------------------
__device__ void spatial_body(const bf16* __restrict__ qk,
                             float* __restrict__ out1, bf16* __restrict__ swB,
                             int ct, int b, char* smem){
  bf16* Qall = (bf16*)smem;             // 16*512 (16384 B)
  bf16* Ks   = (bf16*)(smem + 16384);   // 256*64 (32768 B)
  float* redM  = (float*)(smem + 49152);   // 4*16
  float* redS2 = (float*)(smem + 49408);   // 4*16
  int tid = threadIdx.x;
  int w = tid>>6, lane = tid&63, quad = lane>>4, l16 = lane&15;
  const bf16* qbase = qk + ((size_t)(b*256 + ct*16))*1024;
  #pragma unroll
  for (int c=0;c<4;c++){
    int ch = tid + c*256;
    int row = ch>>6, p = ch&63;
    gl_lds16(qbase + (size_t)row*1024 + ((p ^ (row&7))*8), &Qall[row*512 + p*8]);
  }
  float fRes[4][4];
  #pragma unroll
  for (int j=0;j<4;j++)
    #pragma unroll
    for (int e=0;e<4;e++) fRes[j][e] = 0.0f;

  for (int h=0; h<8; ++h){
    __syncthreads();
    #pragma unroll
    for (int c=0;c<8;c++){
      int ch = tid + c*256;
      int e = ch>>3, p = ch&7;
      gl_lds16(qk + ((size_t)(b*256 + e))*1024 + 512 + h*64 + ((p ^ (e&7))*8),
               &Ks[e*64 + p*8]);
    }
    __syncthreads();
    f32x4 acc[4];
    #pragma unroll
    for (int j=0;j<4;j++) acc[j] = (f32x4){0.f,0.f,0.f,0.f};
    #pragma unroll
    for (int ks=0; ks<2; ++ks){
      int g = h*8 + ks*4 + quad;
      short8 aq = *(short8*)&Qall[l16*512 + ((g ^ (l16&7))*8)];
      #pragma unroll
      for (int j=0;j<4;j++){
        int e = w*64 + j*16 + l16;
        short8 bk = *(short8*)&Ks[e*64 + (((ks*4+quad) ^ (e&7))*8)];
        acc[j] = __builtin_amdgcn_mfma_f32_16x16x32_bf16(aq, bk, acc[j], 0,0,0);
      }
    }
    #pragma unroll
    for (int e=0;e<4;e++){
      float m = -3.0e38f;
      #pragma unroll
      for (int j=0;j<4;j++){
        float s = acc[j][e]*0.125f;
        acc[j][e] = s;
        m = fmaxf(m, s);
      }
      #pragma unroll
      for (int off=1; off<16; off<<=1) m = fmaxf(m, __shfl_xor(m, off, 16));
      if (l16==0) redM[w*16 + quad*4+e] = m;
    }
    __syncthreads();
    #pragma unroll
    for (int e=0;e<4;e++){
      int r = quad*4+e;
      float m = fmaxf(fmaxf(redM[r],redM[16+r]), fmaxf(redM[32+r],redM[48+r]));
      float s = 0.0f;
      #pragma unroll
      for (int j=0;j<4;j++){
        float p = __expf(acc[j][e]-m);
        acc[j][e] = p; s += p;
      }
      #pragma unroll
      for (int off=1; off<16; off<<=1) s += __shfl_xor(s, off, 16);
      if (l16==0) redS2[w*16 + r] = s;
    }
    __syncthreads();
    #pragma unroll
    for (int e=0;e<4;e++){
      int r = quad*4+e;
      float tot = redS2[r]+redS2[16+r]+redS2[32+r]+redS2[48+r];
      float inv = 0.125f/tot;
      #pragma unroll
      for (int j=0;j<4;j++) fRes[j][e] += acc[j][e]*inv;
    }
  }
  #pragma unroll
  for (int e=0;e<4;e++){
    int c = ct*16 + quad*4 + e;
    size_t rb = ((size_t)b*256 + c)*256;
    #pragma unroll
    for (int j=0;j<4;j++){
      int col = w*64 + j*16 + l16;
      out1[rb+col] = fRes[j][e];
      swB[rb+col]  = __float2bfloat16(fRes[j][e]);
    }
  }
}

// ---- co-launch: flash (1024 blocks, longest-qt-first) + spatial (256) -----
__global__ __launch_bounds__(256) void flash_spatial(
    const bf16* __restrict__ qkv, bf16* __restrict__ o,
    const bf16* __restrict__ qk, float* __restrict__ out1,
    bf16* __restrict__ swB){
  __shared__ __align__(16) char smem[49664];   // union: flash 22KB / spatial 48.5KB
  int id = blockIdx.x;
  if (id < 1024){
    int b = id >> 6, h = (id >> 3) & 7, qt = 7 - (id & 7);
    flash_body(qkv, o, qt, h, b, smem);
  } else {
    int t = id - 1024;
    spatial_body(qk, out1, swB, t & 15, t >> 4, smem);
  }
}

extern "C" void kernel_launch(void* const* d_in, const int* in_sizes, int n_in,
                              void* d_out, int out_size, void* d_ws, size_t ws_size,
                              hipStream_t stream){
  (void)in_sizes; (void)n_in; (void)out_size; (void)ws_size;
  const float* x_T  = (const float*)d_in[0];
  const float* x_S  = (const float*)d_in[1];
  const float* Wq_t = (const float*)d_in[2];
  const float* Wk_t = (const float*)d_in[3];
  const float* Wv_t = (const float*)d_in[4];
  const float* Wo   = (const float*)d_in[5];
  const float* Wq_s = (const float*)d_in[6];
  const float* Wk_s = (const float*)d_in[7];
  const float* f1w1 = (const float*)d_in[8];
  const float* f1b1 = (const float*)d_in[9];
  const float* f1w2 = (const float*)d_in[10];
  const float* f1b2 = (const float*)d_in[11];
  const float* f2w1 = (const float*)d_in[12];
  const float* f2b1 = (const float*)d_in[13];
  const float* f2w2 = (const float*)d_in[14];
  const float* f2b2 = (const float*)d_in[15];
  const float* tl1w = (const float*)d_in[16];
  const float* tl1b = (const float*)d_in[17];
  const float* tl2w = (const float*)d_in[18];
  const float* tl2b = (const float*)d_in[19];
  const float* sl1w = (const float*)d_in[20];
  const float* sl1b = (const float*)d_in[21];
  const float* flw  = (const float*)d_in[22];
  const float* flb  = (const float*)d_in[23];

  float* ws = (float*)d_ws;
  size_t off = 0;
  bf16*  Wqkvb  = (bf16*)(ws + off); off += 768*256/2;
  bf16*  Wob    = (bf16*)(ws + off); off += 256*256/2;
  bf16*  f1w1b  = (bf16*)(ws + off); off += 1024*256/2;
  bf16*  f1w2b  = (bf16*)(ws + off); off += 256*1024/2;
  bf16*  f2w1b  = (bf16*)(ws + off); off += 1024*256/2;
  bf16*  f2w2b  = (bf16*)(ws + off); off += 256*1024/2;
  bf16*  WSb    = (bf16*)(ws + off); off += 1024*512/2;
  bf16*  bufHb  = (bf16*)(ws + off); off += (size_t)8192*256/2;
  bf16*  bufHSb = (bf16*)(ws + off); off += (size_t)4096*512/2;
  bf16*  bufQKVb= (bf16*)(ws + off); off += (size_t)8192*768/2;
  bf16*  bufBigB= (bf16*)(ws + off); off += (size_t)8192*1024/2;
  bf16*  bufOb  = (bf16*)(ws + off); off += (size_t)8192*256/2;
  bf16*  bufTOb = (bf16*)(ws + off); off += (size_t)8192*256/2;
  bf16*  swB    = (bf16*)(ws + off); off += (size_t)16*256*256/2;
  bf16*  qkB    = (bf16*)(ws + off); off += (size_t)4096*1024/2;
  float* bufX   = ws + off; off += (size_t)8192*256;
  float* bufTO  = ws + off; off += (size_t)8192*256;
  float* bufX2  = ws + off; off += (size_t)8192*256;

  float* out0 = (float*)d_out;                      // [B,T,C]
  float* out1 = out0 + (size_t)16*512*256;          // spatial_weights [B,C,C]

  // 1. prologue: weight prep + LN(x_T) + LN(x_S)
  ProArgs pa;
  pa.wsrc[0]=Wq_t;  pa.wdst[0]=Wqkvb;
  pa.wsrc[1]=Wk_t;  pa.wdst[1]=Wqkvb+65536;
  pa.wsrc[2]=Wv_t;  pa.wdst[2]=Wqkvb+131072;
  pa.wsrc[3]=Wo;    pa.wdst[3]=Wob;
  pa.wsrc[4]=f1w1;  pa.wdst[4]=f1w1b;
  pa.wsrc[5]=f1w2;  pa.wdst[5]=f1w2b;
  pa.wsrc[6]=f2w1;  pa.wdst[6]=f2w1b;
  pa.wsrc[7]=f2w2;  pa.wdst[7]=f2w2b;
  pa.wsrc[8]=Wq_s;  pa.wdst[8]=WSb;
  pa.wsrc[9]=Wk_s;  pa.wdst[9]=WSb+262144;
  pa.xT=x_T; pa.xS=x_S; pa.tl1w=tl1w; pa.tl1b=tl1b;
  pa.sl1w=sl1w; pa.sl1b=sl1b; pa.hT=bufHb; pa.hS=bufHSb;
  prologue<<<14080,256,0,stream>>>(pa);

  // 2. dual: qkv (384 tiles) + spatial projection (256 tiles)
  GArgs gq, gs;
  gq.A=bufHb;  gq.B=Wqkvb; gq.outF=nullptr; gq.outB=bufQKVb;
  gq.bias=nullptr; gq.resid=nullptr;
  gq.K=256; gq.lda=256; gq.ldb=256; gq.ldc=768; gq.flags=0; gq.ty=6;
  gs.A=bufHSb; gs.B=WSb;   gs.outF=nullptr; gs.outB=qkB;
  gs.bias=nullptr; gs.resid=nullptr;
  gs.K=512; gs.lda=512; gs.ldb=512; gs.ldc=1024; gs.flags=0; gs.ty=8;
  gemm_dual<<<640,256,0,stream>>>(gq, gs, 384);

  // 3. flash (temporal attention) + fused spatial attention, co-launched
  flash_spatial<<<1280,256,0,stream>>>(bufQKVb, bufOb, qkB, out1, swB);

  // 4. x = o @ Wo^T + x_T ; h2 = LN(x)  (fused, BM=32, 256 blocks)
  gemm_ln<<<dim3(256,1,1),256,0,stream>>>(bufOb, Wob, bufX, bufHb,
        x_T, tl2w, tl2b, 256, 256,256, F_RES, 0,0,0,0);
  // 5. f1 = relu(h2 @ w1^T + b1) -> bf16
  gemm_mfma<128,64><<<dim3(64,8),256,0,stream>>>(bufHb, f1w1b, nullptr, bufBigB,
        f1b1, nullptr, 256, 256,256,1024, F_BIAS|F_RELU);
  // 6. temporal_out = f1 @ w2^T + b2 + x -> fp32 + bf16
  gemm_mfma<64,64><<<dim3(128,2),256,0,stream>>>(bufBigB, f1w2b, bufTO, bufTOb,
        f1b2, bufX, 1024, 1024,1024,256, F_BIAS|F_RES);
  // 7. x2 = TO @ sw[b]^T + TO ; h3 = LN(x2)  (fused, batched, 256 blocks)
  gemm_ln<<<dim3(16,1,16),256,0,stream>>>(bufTOb, swB, bufX2, bufHb,
        bufTO, flw, flb, 256, 256,256, F_RES,
        131072, 65536, 131072, 131072);
  // 8. f2 hidden -> bf16
  gemm_mfma<128,64><<<dim3(64,8),256,0,stream>>>(bufHb, f2w1b, nullptr, bufBigB,
        f2b1, nullptr, 256, 256,256,1024, F_BIAS|F_RELU);
  // 9. out = f2 @ w2^T + b2 + x2 -> fp32 d_out
  gemm_mfma<64,64><<<dim3(128,2),256,0,stream>>>(bufBigB, f2w2b, out0, nullptr,
        f2b2, bufX2, 1024, 1024,1024,256, F_BIAS|F_RES);
}

// Round 14
// 286.241 us; speedup vs baseline: 1.1956x; 1.0487x over previous
//
#include <hip/hip_runtime.h>
#include <hip/hip_bf16.h>

typedef __hip_bfloat16 bf16;
typedef __attribute__((ext_vector_type(8))) short short8;
typedef __attribute__((ext_vector_type(4))) float f32x4;

#define F_BIAS 1
#define F_RELU 2
#define F_RES  4

__device__ __forceinline__ void st_out(float* p, float v){ *p = v; }
__device__ __forceinline__ void st_out(bf16* p, float v){ *p = __float2bfloat16(v); }
__device__ __forceinline__ short f2bs(float f){
  bf16 h = __float2bfloat16(f);
  return *reinterpret_cast<short*>(&h);
}

// async global->LDS, 16 B per lane.
__device__ __forceinline__ void gl_lds16(const void* g, void* l){
  __builtin_amdgcn_global_load_lds(
      (const __attribute__((address_space(1))) void*)g,
      (__attribute__((address_space(3))) void*)l, 16, 0, 0);
}

// ---------------- prologue: weight prep + LN(x_T) + LN(x_S) ----------------
struct ProArgs {
  const float* wsrc[10];
  bf16* wdst[10];
  const float *xT, *xS, *tl1w, *tl1b, *sl1w, *sl1b;
  bf16 *hT, *hS;
};

__device__ void ln_body(bf16* __restrict__ dst, const float* __restrict__ src,
                        const float* __restrict__ w, const float* __restrict__ bvec,
                        int row, int rowLen){
  int tid = threadIdx.x;
  const float* s = src + (size_t)row*rowLen;
  float x0 = s[tid];
  float x1 = (rowLen > 256) ? s[tid+256] : 0.0f;
  float sum = x0 + x1, sq = x0*x0 + x1*x1;
  #pragma unroll
  for (int off=32; off; off>>=1){
    sum += __shfl_down(sum, off, 64);
    sq  += __shfl_down(sq , off, 64);
  }
  __shared__ float sbs[4], sbq[4];
  int wid = tid>>6, lane = tid&63;
  if (lane==0){ sbs[wid]=sum; sbq[wid]=sq; }
  __syncthreads();
  if (tid==0){
    float a=0, b2=0;
    for (int i=0;i<4;i++){ a+=sbs[i]; b2+=sbq[i]; }
    sbs[0]=a; sbq[0]=b2;
  }
  __syncthreads();
  float inv  = 1.0f/(float)rowLen;
  float mean = sbs[0]*inv;
  float var  = sbq[0]*inv - mean*mean;
  float rstd = rsqrtf(var + 1e-6f);
  bf16* d = dst + (size_t)row*rowLen;
  d[tid] = __float2bfloat16((x0-mean)*rstd*w[tid] + bvec[tid]);
  if (rowLen > 256)
    d[tid+256] = __float2bfloat16((x1-mean)*rstd*w[tid+256] + bvec[tid+256]);
}

__global__ __launch_bounds__(256) void prologue(ProArgs a){
  int blk = blockIdx.x;
  if (blk < 1792){
    int v = blk*256 + threadIdx.x;
    int e = v*4;
    int seg = (e>=65536)+(e>=131072)+(e>=196608)+(e>=262144)+(e>=524288)
            + (e>=786432)+(e>=1048576)+(e>=1310720)+(e>=1572864);
    const int starts[10] = {0,65536,131072,196608,262144,524288,786432,
                            1048576,1310720,1572864};
    int off = e - starts[seg];
    float4 f = *(const float4*)(a.wsrc[seg] + off);
    short4 o;
    o.x = f2bs(f.x); o.y = f2bs(f.y); o.z = f2bs(f.z); o.w = f2bs(f.w);
    *(short4*)((short*)a.wdst[seg] + off) = o;
  } else if (blk < 1792 + 8192){
    ln_body(a.hT, a.xT, a.tl1w, a.tl1b, blk-1792, 256);
  } else {
    ln_body(a.hS, a.xS, a.sl1w, a.sl1b, blk-9984, 512);
  }
}

// ---------------- MFMA bf16 GEMM body (swizzled gl_lds16, BN=128) ----------
template<int BM, int BK>
__device__ __forceinline__ void gemm_body(
    const bf16* __restrict__ A, const bf16* __restrict__ B,
    float* __restrict__ outF, bf16* __restrict__ outB,
    const float* __restrict__ bias, const float* __restrict__ resid,
    int K, int lda, int ldb, int ldc, int flags, int m0, int n0){
  __shared__ short As[BM*BK];
  __shared__ short Bs[128*BK];
  int tid = threadIdx.x;
  int w = tid>>6, lane = tid&63, quad = lane>>4, l16 = lane&15;
  constexpr int WM = BM/2;
  constexpr int MF = WM/16;
  constexpr int CPR = BK/8;
  constexpr int CA = BM*CPR/256;
  constexpr int CB = 128*CPR/256;
  int wm = (w>>1)*WM, wn = (w&1)*64;
  f32x4 acc[MF][4];
  #pragma unroll
  for (int r=0;r<MF;r++)
    #pragma unroll
    for (int j=0;j<4;j++)
      acc[r][j] = (f32x4){0.f,0.f,0.f,0.f};

  for (int k0 = 0; k0 < K; k0 += BK){
    #pragma unroll
    for (int c=0;c<CA;c++){
      int ch = tid + c*256;
      int row = ch / CPR, p = ch % CPR;
      gl_lds16(A + (size_t)(m0+row)*lda + k0 + ((p ^ (row&(CPR-1)))*8),
               &As[row*BK + p*8]);
    }
    #pragma unroll
    for (int c=0;c<CB;c++){
      int ch = tid + c*256;
      int row = ch / CPR, p = ch % CPR;
      gl_lds16(B + (size_t)(n0+row)*ldb + k0 + ((p ^ (row&(CPR-1)))*8),
               &Bs[row*BK + p*8]);
    }
    __syncthreads();
    #pragma unroll
    for (int ks=0; ks<BK/32; ++ks){
      short8 af[MF], bfr[4];
      #pragma unroll
      for (int r=0;r<MF;r++){
        int rr = wm + r*16 + l16;
        af[r] = *(short8*)&As[rr*BK + (((ks*4+quad) ^ (rr&(CPR-1)))*8)];
      }
      #pragma unroll
      for (int j=0;j<4;j++){
        int rr = wn + j*16 + l16;
        bfr[j] = *(short8*)&Bs[rr*BK + (((ks*4+quad) ^ (rr&(CPR-1)))*8)];
      }
      #pragma unroll
      for (int r=0;r<MF;r++)
        #pragma unroll
        for (int j=0;j<4;j++)
          acc[r][j] = __builtin_amdgcn_mfma_f32_16x16x32_bf16(af[r], bfr[j], acc[r][j], 0,0,0);
    }
    __syncthreads();
  }
  #pragma unroll
  for (int r=0;r<MF;r++){
    int mb = m0 + wm + r*16 + quad*4;
    #pragma unroll
    for (int j=0;j<4;j++){
      int n = n0 + wn + j*16 + l16;
      float bv = (flags & F_BIAS) ? bias[n] : 0.0f;
      #pragma unroll
      for (int e=0;e<4;e++){
        float v = acc[r][j][e] + bv;
        if (flags & F_RELU) v = fmaxf(v, 0.0f);
        long long idx = (long long)(mb+e)*ldc + n;
        if (flags & F_RES) v += resid[idx];
        if (outF) outF[idx] = v;
        if (outB) st_out(outB + idx, v);
      }
    }
  }
}

template<int BM, int BK>
__global__ __launch_bounds__(256) void gemm_mfma(
    const bf16* __restrict__ A, const bf16* __restrict__ B,
    float* __restrict__ outF, bf16* __restrict__ outB,
    const float* __restrict__ bias, const float* __restrict__ resid,
    int K, int lda, int ldb, int ldc, int flags){
  gemm_body<BM,BK>(A,B,outF,outB,bias,resid,K,lda,ldb,ldc,flags,
                   blockIdx.x*BM, blockIdx.y*128);
}

// ---- dual GEMM: two independent <128,64> GEMMs in one launch (1-D grid) ----
struct GArgs {
  const bf16 *A, *B;
  float* outF; bf16* outB;
  const float *bias, *resid;
  int K, lda, ldb, ldc, flags, ty;
};
__global__ __launch_bounds__(256) void gemm_dual(GArgs g0, GArgs g1, int n0){
  int id = blockIdx.x;
  bool first = id < n0;
  const GArgs& g = first ? g0 : g1;
  int t = first ? id : id - n0;
  int bx = t / g.ty, by = t - bx*g.ty;
  gemm_body<128,64>(g.A, g.B, g.outF, g.outB, g.bias, g.resid,
                    g.K, g.lda, g.ldb, g.ldc, g.flags, bx*128, by*128);
}

// ------- MFMA GEMM + fused row-LN epilogue (BM=32, N=ldc=256, BK=64) -------
__global__ __launch_bounds__(256) void gemm_ln(
    const bf16* __restrict__ A, const bf16* __restrict__ B,
    float* __restrict__ outF, bf16* __restrict__ outLN,
    const float* __restrict__ resid,
    const float* __restrict__ lnw, const float* __restrict__ lnb,
    int K, int lda, int ldb, int flags,
    long long sA, long long sB, long long sO, long long sR){
  int bz = blockIdx.z;
  A += (size_t)bz*sA;
  B += (size_t)bz*sB;
  long long obase = (long long)bz*sO;
  __shared__ short As[32*64];
  __shared__ short Bs[256*64];
  __shared__ float redS[2][32], redQ[2][32];
  int tid = threadIdx.x;
  int m0 = blockIdx.x*32;
  int w = tid>>6, lane = tid&63, quad = lane>>4, l16 = lane&15;
  int wm = (w>>1)*16, wn = (w&1)*128;
  f32x4 acc[8];
  #pragma unroll
  for (int j=0;j<8;j++) acc[j] = (f32x4){0.f,0.f,0.f,0.f};

  for (int k0 = 0; k0 < K; k0 += 64){
    {
      int row = tid >> 3, p = tid & 7;
      gl_lds16(A + (size_t)(m0+row)*lda + k0 + ((p ^ (row&7))*8),
               &As[row*64 + p*8]);
    }
    #pragma unroll
    for (int c=0;c<8;c++){
      int ch = tid + c*256;
      int row = ch >> 3, p = ch & 7;
      gl_lds16(B + (size_t)row*ldb + k0 + ((p ^ (row&7))*8),
               &Bs[row*64 + p*8]);
    }
    __syncthreads();
    #pragma unroll
    for (int ks=0; ks<2; ++ks){
      int rr = wm + l16;
      short8 af = *(short8*)&As[rr*64 + (((ks*4+quad) ^ (rr&7))*8)];
      #pragma unroll
      for (int j=0;j<8;j++){
        int rb = wn + j*16 + l16;
        short8 bfr = *(short8*)&Bs[rb*64 + (((ks*4+quad) ^ (rb&7))*8)];
        acc[j] = __builtin_amdgcn_mfma_f32_16x16x32_bf16(af, bfr, acc[j], 0,0,0);
      }
    }
    __syncthreads();
  }
  #pragma unroll
  for (int e=0;e<4;e++){
    int row = wm + quad*4 + e;
    float s = 0.f, q2 = 0.f;
    #pragma unroll
    for (int j=0;j<8;j++){
      float v = acc[j][e];
      if (flags & F_RES)
        v += resid[(long long)bz*sR + (long long)(m0+row)*256 + wn + j*16 + l16];
      acc[j][e] = v;
      s += v; q2 += v*v;
    }
    #pragma unroll
    for (int off=1; off<16; off<<=1){
      s  += __shfl_xor(s , off, 16);
      q2 += __shfl_xor(q2, off, 16);
    }
    if (l16==0){ redS[w&1][row] = s; redQ[w&1][row] = q2; }
  }
  __syncthreads();
  #pragma unroll
  for (int e=0;e<4;e++){
    int row = wm + quad*4 + e;
    float tot = redS[0][row] + redS[1][row];
    float tq  = redQ[0][row] + redQ[1][row];
    float mean = tot * (1.0f/256.0f);
    float var  = tq * (1.0f/256.0f) - mean*mean;
    float rstd = rsqrtf(var + 1e-6f);
    #pragma unroll
    for (int j=0;j<8;j++){
      int col = wn + j*16 + l16;
      float v = acc[j][e];
      long long idx = obase + (long long)(m0+row)*256 + col;
      if (outF) outF[idx] = v;
      outLN[idx] = __float2bfloat16((v-mean)*rstd*lnw[col] + lnb[col]);
    }
  }
}

// ---------------- MFMA flash temporal causal attention ----------------
__device__ __forceinline__ int fsw(int row){ return (row>>1)&3; }
__global__ __launch_bounds__(256) void flash_mfma(
    const bf16* __restrict__ qkv, bf16* __restrict__ o){
  int qt = (int)gridDim.x - 1 - (int)blockIdx.x;   // longest blocks first
  int h = blockIdx.y, b = blockIdx.z;
  int tid = threadIdx.x;
  int w = tid>>6, lane = tid&63, quad = lane>>4, l16 = lane&15;
  __shared__ bf16 Qs[64*32];
  __shared__ bf16 Ks[64*32];
  __shared__ bf16 Vt[32*72];
  __shared__ bf16 Ps[64*72];
  const bf16* base = qkv + (size_t)b*512*768;
  int t0 = qt*64;
  int srow = tid>>2, spos = tid&3;
  gl_lds16(base + (size_t)(t0+srow)*768 + h*32 + ((spos ^ fsw(srow))*8),
           &Qs[srow*32 + spos*8]);
  f32x4 accO[2];
  accO[0] = (f32x4){0.f,0.f,0.f,0.f};
  accO[1] = (f32x4){0.f,0.f,0.f,0.f};
  float m_i[4], l_i[4];
  #pragma unroll
  for (int e=0;e<4;e++){ m_i[e] = -3.0e38f; l_i[e] = 0.0f; }
  const float scale = 0.17677669529663687f;

  for (int kt = 0; kt <= qt; ++kt){
    int s0 = kt*64;
    __syncthreads();
    {
      const bf16* rp = base + (size_t)(s0+srow)*768 + h*32;
      gl_lds16(rp + 256 + ((spos ^ fsw(srow))*8), &Ks[srow*32 + spos*8]);
      short8 v = *(const short8*)(rp + 512 + spos*8);
      #pragma unroll
      for (int q=0;q<8;q++){
        short tmp = v[q];
        Vt[(spos*8+q)*72 + srow] = *(bf16*)&tmp;
      }
    }
    __syncthreads();
    int rq = w*16 + l16;
    short8 aq = *(short8*)&Qs[rq*32 + ((quad ^ fsw(rq))*8)];
    f32x4 S[4];
    #pragma unroll
    for (int j2=0;j2<4;j2++){
      int rk = j2*16 + l16;
      short8 bk = *(short8*)&Ks[rk*32 + ((quad ^ fsw(rk))*8)];
      S[j2] = __builtin_amdgcn_mfma_f32_16x16x32_bf16(aq, bk,
                (f32x4){0.f,0.f,0.f,0.f}, 0,0,0);
    }
    bool diag = (kt == qt);
    int qrow_base = t0 + w*16 + quad*4;
    #pragma unroll
    for (int e=0;e<4;e++){
      float sv[4];
      #pragma unroll
      for (int j2=0;j2<4;j2++){
        float x = S[j2][e]*scale;
        if (diag && (s0 + j2*16 + l16 > qrow_base + e)) x = -3.0e38f;
        sv[j2] = x;
      }
      float mx = fmaxf(fmaxf(sv[0],sv[1]), fmaxf(sv[2],sv[3]));
      #pragma unroll
      for (int off=1; off<16; off<<=1) mx = fmaxf(mx, __shfl_xor(mx, off, 64));
      float m_new = fmaxf(m_i[e], mx);
      float alpha = __expf(m_i[e]-m_new);
      float rs = 0.0f;
      #pragma unroll
      for (int j2=0;j2<4;j2++){
        float p = __expf(sv[j2]-m_new);
        rs += p;
        Ps[(w*16+quad*4+e)*72 + j2*16 + l16] = __float2bfloat16(p);
      }
      #pragma unroll
      for (int off=1; off<16; off<<=1) rs += __shfl_xor(rs, off, 64);
      l_i[e] = l_i[e]*alpha + rs;
      m_i[e] = m_new;
      accO[0][e] *= alpha;
      accO[1][e] *= alpha;
    }
    __syncthreads();
    #pragma unroll
    for (int sh=0; sh<2; ++sh){
      short8 ap = *(short8*)&Ps[(w*16+l16)*72 + sh*32 + quad*8];
      #pragma unroll
      for (int dh=0; dh<2; ++dh){
        short8 bv = *(short8*)&Vt[(dh*16+l16)*72 + sh*32 + quad*8];
        accO[dh] = __builtin_amdgcn_mfma_f32_16x16x32_bf16(ap, bv, accO[dh], 0,0,0);
      }
    }
  }
  #pragma unroll
  for (int e=0;e<4;e++){
    float inv = 1.0f/l_i[e];
    int t = t0 + w*16 + quad*4 + e;
    bf16* op = o + ((size_t)(b*512+t))*256 + h*32 + l16;
    op[0]  = __float2bfloat16(accO[0][e]*inv);
    op[16] = __float2bfloat16(accO[1][e]*inv);
  }
}

// ------- fused spatial attention body (scores + softmax + head-mean) -------
__device__ void spatial_body(const bf16* __restrict__ qk,
                             float* __restrict__ out1, bf16* __restrict__ swB,
                             int ct, int b){
  int tid = threadIdx.x;
  int w = tid>>6, lane = tid&63, quad = lane>>4, l16 = lane&15;
  __shared__ bf16 Qall[16*512];
  __shared__ bf16 Ks[256*64];
  __shared__ float redM[4][16], redS2[4][16];
  const bf16* qbase = qk + ((size_t)(b*256 + ct*16))*1024;
  #pragma unroll
  for (int c=0;c<4;c++){
    int ch = tid + c*256;
    int row = ch>>6, p = ch&63;
    gl_lds16(qbase + (size_t)row*1024 + ((p ^ (row&7))*8), &Qall[row*512 + p*8]);
  }
  float fRes[4][4];
  #pragma unroll
  for (int j=0;j<4;j++)
    #pragma unroll
    for (int e=0;e<4;e++) fRes[j][e] = 0.0f;

  for (int h=0; h<8; ++h){
    __syncthreads();
    #pragma unroll
    for (int c=0;c<8;c++){
      int ch = tid + c*256;
      int e = ch>>3, p = ch&7;
      gl_lds16(qk + ((size_t)(b*256 + e))*1024 + 512 + h*64 + ((p ^ (e&7))*8),
               &Ks[e*64 + p*8]);
    }
    __syncthreads();
    f32x4 acc[4];
    #pragma unroll
    for (int j=0;j<4;j++) acc[j] = (f32x4){0.f,0.f,0.f,0.f};
    #pragma unroll
    for (int ks=0; ks<2; ++ks){
      int g = h*8 + ks*4 + quad;
      short8 aq = *(short8*)&Qall[l16*512 + ((g ^ (l16&7))*8)];
      #pragma unroll
      for (int j=0;j<4;j++){
        int e = w*64 + j*16 + l16;
        short8 bk = *(short8*)&Ks[e*64 + (((ks*4+quad) ^ (e&7))*8)];
        acc[j] = __builtin_amdgcn_mfma_f32_16x16x32_bf16(aq, bk, acc[j], 0,0,0);
      }
    }
    #pragma unroll
    for (int e=0;e<4;e++){
      float m = -3.0e38f;
      #pragma unroll
      for (int j=0;j<4;j++){
        float s = acc[j][e]*0.125f;
        acc[j][e] = s;
        m = fmaxf(m, s);
      }
      #pragma unroll
      for (int off=1; off<16; off<<=1) m = fmaxf(m, __shfl_xor(m, off, 16));
      if (l16==0) redM[w][quad*4+e] = m;
    }
    __syncthreads();
    #pragma unroll
    for (int e=0;e<4;e++){
      int r = quad*4+e;
      float m = fmaxf(fmaxf(redM[0][r],redM[1][r]), fmaxf(redM[2][r],redM[3][r]));
      float s = 0.0f;
      #pragma unroll
      for (int j=0;j<4;j++){
        float p = __expf(acc[j][e]-m);
        acc[j][e] = p; s += p;
      }
      #pragma unroll
      for (int off=1; off<16; off<<=1) s += __shfl_xor(s, off, 16);
      if (l16==0) redS2[w][r] = s;
    }
    __syncthreads();
    #pragma unroll
    for (int e=0;e<4;e++){
      int r = quad*4+e;
      float tot = redS2[0][r]+redS2[1][r]+redS2[2][r]+redS2[3][r];
      float inv = 0.125f/tot;
      #pragma unroll
      for (int j=0;j<4;j++) fRes[j][e] += acc[j][e]*inv;
    }
  }
  #pragma unroll
  for (int e=0;e<4;e++){
    int c = ct*16 + quad*4 + e;
    size_t rb = ((size_t)b*256 + c)*256;
    #pragma unroll
    for (int j=0;j<4;j++){
      int col = w*64 + j*16 + l16;
      out1[rb+col] = fRes[j][e];
      swB[rb+col]  = __float2bfloat16(fRes[j][e]);
    }
  }
}

// ---- mixed launch: f1b GEMM (256 tiles) + spatial_fused (256 blocks) ------
__global__ __launch_bounds__(256) void mixed_l2(
    const bf16* __restrict__ gA, const bf16* __restrict__ gB,
    float* __restrict__ gOutF, bf16* __restrict__ gOutB,
    const float* __restrict__ gBias, const float* __restrict__ gResid,
    const bf16* __restrict__ qk, float* __restrict__ out1,
    bf16* __restrict__ swB){
  int id = blockIdx.x;
  if (id < 256){
    int bx = id >> 1, by = id & 1;
    gemm_body<64,64>(gA, gB, gOutF, gOutB, gBias, gResid,
                     1024, 1024, 1024, 256, F_BIAS|F_RES, bx*64, by*128);
  } else {
    int t = id - 256;
    spatial_body(qk, out1, swB, t & 15, t >> 4);
  }
}

extern "C" void kernel_launch(void* const* d_in, const int* in_sizes, int n_in,
                              void* d_out, int out_size, void* d_ws, size_t ws_size,
                              hipStream_t stream){
  (void)in_sizes; (void)n_in; (void)out_size; (void)ws_size;
  const float* x_T  = (const float*)d_in[0];
  const float* x_S  = (const float*)d_in[1];
  const float* Wq_t = (const float*)d_in[2];
  const float* Wk_t = (const float*)d_in[3];
  const float* Wv_t = (const float*)d_in[4];
  const float* Wo   = (const float*)d_in[5];
  const float* Wq_s = (const float*)d_in[6];
  const float* Wk_s = (const float*)d_in[7];
  const float* f1w1 = (const float*)d_in[8];
  const float* f1b1 = (const float*)d_in[9];
  const float* f1w2 = (const float*)d_in[10];
  const float* f1b2 = (const float*)d_in[11];
  const float* f2w1 = (const float*)d_in[12];
  const float* f2b1 = (const float*)d_in[13];
  const float* f2w2 = (const float*)d_in[14];
  const float* f2b2 = (const float*)d_in[15];
  const float* tl1w = (const float*)d_in[16];
  const float* tl1b = (const float*)d_in[17];
  const float* tl2w = (const float*)d_in[18];
  const float* tl2b = (const float*)d_in[19];
  const float* sl1w = (const float*)d_in[20];
  const float* sl1b = (const float*)d_in[21];
  const float* flw  = (const float*)d_in[22];
  const float* flb  = (const float*)d_in[23];

  float* ws = (float*)d_ws;
  size_t off = 0;
  bf16*  Wqkvb  = (bf16*)(ws + off); off += 768*256/2;
  bf16*  Wob    = (bf16*)(ws + off); off += 256*256/2;
  bf16*  f1w1b  = (bf16*)(ws + off); off += 1024*256/2;
  bf16*  f1w2b  = (bf16*)(ws + off); off += 256*1024/2;
  bf16*  f2w1b  = (bf16*)(ws + off); off += 1024*256/2;
  bf16*  f2w2b  = (bf16*)(ws + off); off += 256*1024/2;
  bf16*  WSb    = (bf16*)(ws + off); off += 1024*512/2;
  bf16*  bufHb  = (bf16*)(ws + off); off += (size_t)8192*256/2;
  bf16*  bufHSb = (bf16*)(ws + off); off += (size_t)4096*512/2;
  bf16*  bufQKVb= (bf16*)(ws + off); off += (size_t)8192*768/2;
  bf16*  bufBigB= (bf16*)(ws + off); off += (size_t)8192*1024/2;
  bf16*  bufOb  = (bf16*)(ws + off); off += (size_t)8192*256/2;
  bf16*  bufTOb = (bf16*)(ws + off); off += (size_t)8192*256/2;
  bf16*  swB    = (bf16*)(ws + off); off += (size_t)16*256*256/2;
  bf16*  qkB    = (bf16*)(ws + off); off += (size_t)4096*1024/2;
  float* bufX   = ws + off; off += (size_t)8192*256;
  float* bufTO  = ws + off; off += (size_t)8192*256;
  float* bufX2  = ws + off; off += (size_t)8192*256;

  float* out0 = (float*)d_out;                      // [B,T,C]
  float* out1 = out0 + (size_t)16*512*256;          // spatial_weights [B,C,C]

  // 1. prologue: weight prep + LN(x_T) + LN(x_S)
  ProArgs pa;
  pa.wsrc[0]=Wq_t;  pa.wdst[0]=Wqkvb;
  pa.wsrc[1]=Wk_t;  pa.wdst[1]=Wqkvb+65536;
  pa.wsrc[2]=Wv_t;  pa.wdst[2]=Wqkvb+131072;
  pa.wsrc[3]=Wo;    pa.wdst[3]=Wob;
  pa.wsrc[4]=f1w1;  pa.wdst[4]=f1w1b;
  pa.wsrc[5]=f1w2;  pa.wdst[5]=f1w2b;
  pa.wsrc[6]=f2w1;  pa.wdst[6]=f2w1b;
  pa.wsrc[7]=f2w2;  pa.wdst[7]=f2w2b;
  pa.wsrc[8]=Wq_s;  pa.wdst[8]=WSb;
  pa.wsrc[9]=Wk_s;  pa.wdst[9]=WSb+262144;
  pa.xT=x_T; pa.xS=x_S; pa.tl1w=tl1w; pa.tl1b=tl1b;
  pa.sl1w=sl1w; pa.sl1b=sl1b; pa.hT=bufHb; pa.hS=bufHSb;
  prologue<<<14080,256,0,stream>>>(pa);

  // 2. dual: qkv (384 tiles) + spatial projection (256 tiles)
  GArgs gq, gs;
  gq.A=bufHb;  gq.B=Wqkvb; gq.outF=nullptr; gq.outB=bufQKVb;
  gq.bias=nullptr; gq.resid=nullptr;
  gq.K=256; gq.lda=256; gq.ldb=256; gq.ldc=768; gq.flags=0; gq.ty=6;
  gs.A=bufHSb; gs.B=WSb;   gs.outF=nullptr; gs.outB=qkB;
  gs.bias=nullptr; gs.resid=nullptr;
  gs.K=512; gs.lda=512; gs.ldb=512; gs.ldc=1024; gs.flags=0; gs.ty=8;
  gemm_dual<<<640,256,0,stream>>>(gq, gs, 384);

  // 3. temporal causal flash attention -> bf16 o
  flash_mfma<<<dim3(8,8,16),256,0,stream>>>(bufQKVb, bufOb);
  // 4. x = o @ Wo^T + x_T ; h2 = LN(x)  (fused, BM=32, 256 blocks)
  gemm_ln<<<dim3(256,1,1),256,0,stream>>>(bufOb, Wob, bufX, bufHb,
        x_T, tl2w, tl2b, 256, 256,256, F_RES, 0,0,0,0);
  // 5. f1 = relu(h2 @ w1^T + b1) -> bf16
  gemm_mfma<128,64><<<dim3(64,8),256,0,stream>>>(bufHb, f1w1b, nullptr, bufBigB,
        f1b1, nullptr, 256, 256,256,1024, F_BIAS|F_RELU);
  // 6. mixed: temporal_out GEMM (f1b) + fused spatial attention
  mixed_l2<<<512,256,0,stream>>>(bufBigB, f1w2b, bufTO, bufTOb, f1b2, bufX,
        qkB, out1, swB);
  // 7. x2 = TO @ sw[b]^T + TO ; h3 = LN(x2)  (fused, batched, 256 blocks)
  gemm_ln<<<dim3(16,1,16),256,0,stream>>>(bufTOb, swB, bufX2, bufHb,
        bufTO, flw, flb, 256, 256,256, F_RES,
        131072, 65536, 131072, 131072);
  // 8. f2 hidden -> bf16
  gemm_mfma<128,64><<<dim3(64,8),256,0,stream>>>(bufHb, f2w1b, nullptr, bufBigB,
        f2b1, nullptr, 256, 256,256,1024, F_BIAS|F_RELU);
  // 9. out = f2 @ w2^T + b2 + x2 -> fp32 d_out
  gemm_mfma<64,64><<<dim3(128,2),256,0,stream>>>(bufBigB, f2w2b, out0, nullptr,
        f2b2, bufX2, 1024, 1024,1024,256, F_BIAS|F_RES);
}